// Round 1
// baseline (328.778 us; speedup 1.0000x reference)
//
#include <hip/hip_runtime.h>

#define B_ 4
#define C_ 256
#define H_ 64
#define W_ 64
#define HW_ 4096
#define G_ 4
#define K_ 7
#define P_ 3
#define KK_ 49
#define KKG_ 196
#define RED_ 32
#define NSTAT_ 16384.0f
#define BN_EPS_ 1e-5f

// ---------------- kernel 0: zero the stats accumulators ----------------
__global__ void k_zero(float* g) {
    if (threadIdx.x < 64) g[threadIdx.x] = 0.0f;
}

// ---------------- kernel 1: red = w_reduce @ x  (per pixel), + stats ----------------
// grid: 64 blocks x 256 threads; thread = one pixel (b,hw)
__global__ __launch_bounds__(256) void k_reduce(const float* __restrict__ x,
                                               const float* __restrict__ wr,
                                               float* __restrict__ red,
                                               float* __restrict__ gsum,
                                               float* __restrict__ gsq) {
    __shared__ float wlds[RED_ * C_];   // [o][c], 32 KiB
    const int tid = threadIdx.x;
    for (int i = tid; i < RED_ * C_; i += 256) wlds[i] = wr[i];
    __syncthreads();

    const int p  = blockIdx.x * 256 + tid;       // pixel index over B*HW
    const int b  = p >> 12;
    const int hw = p & 4095;
    const float* xp = x + (size_t)b * C_ * HW_ + hw;

    float acc[RED_];
#pragma unroll
    for (int o = 0; o < RED_; ++o) acc[o] = 0.0f;

    for (int c = 0; c < C_; ++c) {
        const float v = xp[(size_t)c * HW_];     // coalesced across wave
#pragma unroll
        for (int o = 0; o < RED_; ++o)
            acc[o] = fmaf(wlds[o * C_ + c], v, acc[o]);   // LDS broadcast
    }

    // store red pixel-major: red[p*32 + o]
    float4* rp = (float4*)(red + (size_t)p * RED_);
#pragma unroll
    for (int q = 0; q < 8; ++q)
        rp[q] = make_float4(acc[4*q], acc[4*q+1], acc[4*q+2], acc[4*q+3]);

    // per-channel sum / sumsq: wave shuffle reduce, then one atomic per wave
    const int lane = tid & 63;
#pragma unroll
    for (int o = 0; o < RED_; ++o) {
        float v  = acc[o];
        float sq = acc[o] * acc[o];
#pragma unroll
        for (int off = 32; off > 0; off >>= 1) {
            v  += __shfl_down(v,  off);
            sq += __shfl_down(sq, off);
        }
        if (lane == 0) {
            atomicAdd(&gsum[o], v);
            atomicAdd(&gsq[o],  sq);
        }
    }
}

// ---------------- kernel 2: fold BN stats into scale/shift ----------------
__global__ void k_bn(const float* __restrict__ gsum, const float* __restrict__ gsq,
                     const float* __restrict__ gamma, const float* __restrict__ beta,
                     float* __restrict__ scale, float* __restrict__ shift) {
    const int o = threadIdx.x;
    if (o >= RED_) return;
    const float m   = gsum[o] * (1.0f / NSTAT_);
    const float var = gsq[o] * (1.0f / NSTAT_) - m * m;
    const float inv = rsqrtf(var + BN_EPS_);
    const float sc  = gamma[o] * inv;
    scale[o] = sc;
    shift[o] = beta[o] - m * sc;
}

// ---------------- kernel 3: act = relu(BN(red)); ker = w_span @ act + b_span ----------------
// grid: 64 blocks x 256 threads; thread = one pixel
__global__ __launch_bounds__(256) void k_span(const float* __restrict__ red,
                                              const float* __restrict__ wspan,
                                              const float* __restrict__ bspan,
                                              const float* __restrict__ scale,
                                              const float* __restrict__ shift,
                                              float* __restrict__ ker) {
    __shared__ float wlds[KKG_ * RED_];  // [o][c], ~24.5 KiB
    __shared__ float sc_l[RED_], sh_l[RED_], bs_l[KKG_];
    const int tid = threadIdx.x;
    for (int i = tid; i < KKG_ * RED_; i += 256) wlds[i] = wspan[i];
    if (tid < RED_) { sc_l[tid] = scale[tid]; sh_l[tid] = shift[tid]; }
    if (tid < KKG_) bs_l[tid] = bspan[tid];
    __syncthreads();

    const int p  = blockIdx.x * 256 + tid;
    const int b  = p >> 12;
    const int hw = p & 4095;

    float act[RED_];
    const float4* rp = (const float4*)(red + (size_t)p * RED_);
#pragma unroll
    for (int q = 0; q < 8; ++q) {
        const float4 v = rp[q];
        act[4*q+0] = v.x; act[4*q+1] = v.y; act[4*q+2] = v.z; act[4*q+3] = v.w;
    }
#pragma unroll
    for (int o = 0; o < RED_; ++o)
        act[o] = fmaxf(fmaf(act[o], sc_l[o], sh_l[o]), 0.0f);

    float* kp = ker + (size_t)b * KKG_ * HW_ + hw;
    for (int o = 0; o < KKG_; ++o) {
        float s = bs_l[o];
#pragma unroll
        for (int c = 0; c < RED_; ++c)
            s = fmaf(wlds[o * RED_ + c], act[c], s);   // LDS broadcast
        kp[(size_t)o * HW_] = s;                       // coalesced across wave
    }
}

// ---------------- kernel 4: involution ----------------
// thread per output element, idx over [B][C][H][W]
__global__ __launch_bounds__(256) void k_inv(const float* __restrict__ x,
                                             const float* __restrict__ ker,
                                             float* __restrict__ out) {
    const int idx = blockIdx.x * 256 + threadIdx.x;
    const int w = idx & 63;
    const int h = (idx >> 6) & 63;
    const int c = (idx >> 12) & 255;
    const int b = idx >> 20;
    const int g = c >> 6;

    const float* kp = ker + ((size_t)b * KKG_ + g * KK_) * HW_ + h * 64 + w;
    const float* xp = x + ((size_t)b * C_ + c) * HW_;

    float s = 0.0f;
#pragma unroll
    for (int i = 0; i < K_; ++i) {
        const int hh = h + i - P_;
        if (hh < 0 || hh >= H_) continue;
#pragma unroll
        for (int j = 0; j < K_; ++j) {
            const int ww = w + j - P_;
            if (ww < 0 || ww >= W_) continue;
            s = fmaf(kp[(i * K_ + j) * HW_], xp[hh * 64 + ww], s);
        }
    }
    out[idx] = s;
}

extern "C" void kernel_launch(void* const* d_in, const int* in_sizes, int n_in,
                              void* d_out, int out_size, void* d_ws, size_t ws_size,
                              hipStream_t stream) {
    const float* x     = (const float*)d_in[0];
    const float* wr    = (const float*)d_in[1];
    const float* gamma = (const float*)d_in[2];
    const float* beta  = (const float*)d_in[3];
    const float* wspan = (const float*)d_in[4];
    const float* bspan = (const float*)d_in[5];
    float* out = (float*)d_out;
    float* ws  = (float*)d_ws;

    // workspace layout (floats)
    float* red   = ws;                    // 4*4096*32   = 524288
    float* gsum  = ws + 524288;           // 32
    float* gsq   = gsum + 32;             // 32
    float* scale = gsq + 32;              // 32
    float* shift = scale + 32;            // 32
    float* ker   = shift + 32;            // 4*196*4096  = 3211264

    hipLaunchKernelGGL(k_zero,   dim3(1),     dim3(64),  0, stream, gsum);
    hipLaunchKernelGGL(k_reduce, dim3(64),    dim3(256), 0, stream, x, wr, red, gsum, gsq);
    hipLaunchKernelGGL(k_bn,     dim3(1),     dim3(32),  0, stream, gsum, gsq, gamma, beta, scale, shift);
    hipLaunchKernelGGL(k_span,   dim3(64),    dim3(256), 0, stream, red, wspan, bspan, scale, shift, ker);
    hipLaunchKernelGGL(k_inv,    dim3(16384), dim3(256), 0, stream, x, ker, out);
}

// Round 2
// 253.504 us; speedup vs baseline: 1.2969x; 1.2969x over previous
//
#include <hip/hip_runtime.h>

#define B_ 4
#define C_ 256
#define H_ 64
#define W_ 64
#define HW_ 4096
#define G_ 4
#define K_ 7
#define P_ 3
#define KK_ 49
#define KKG_ 196
#define RED_ 32
#define NPIX_ 16384          // B*HW
#define NSTAT_ 16384.0f
#define BN_EPS_ 1e-5f
#define OCH_ 28              // k_span outputs per chunk (196 = 7*28)

// ---------------- kernel 0: zero the stats accumulators ----------------
__global__ void k_zero(float* g) {
    if (threadIdx.x < 64) g[threadIdx.x] = 0.0f;
}

// ---------------- kernel 1: red = w_reduce @ x (per pixel, o-group split), + stats ----
// grid: (64, 8); block 256 threads. blockIdx.x -> 256 pixels, blockIdx.y -> 4 o-channels.
// red layout: [og][p] as float4  (og = o/4)
__global__ __launch_bounds__(256) void k_reduce(const float* __restrict__ x,
                                               const float* __restrict__ wr,
                                               float4* __restrict__ red,
                                               float* __restrict__ gsum,
                                               float* __restrict__ gsq) {
    __shared__ float wlds[4 * C_];      // 4 rows of w_reduce, 4 KiB
    const int tid = threadIdx.x;
    const int og  = blockIdx.y;         // 0..7
    for (int i = tid; i < 4 * C_; i += 256) wlds[i] = wr[og * 4 * C_ + i];
    __syncthreads();

    const int p  = blockIdx.x * 256 + tid;       // pixel index over B*HW
    const int b  = p >> 12;
    const int hw = p & 4095;
    const float* xp = x + (size_t)b * C_ * HW_ + hw;

    float a0 = 0.f, a1 = 0.f, a2 = 0.f, a3 = 0.f;
#pragma unroll 8
    for (int c = 0; c < C_; ++c) {
        const float v = xp[(size_t)c * HW_];     // coalesced across wave
        a0 = fmaf(wlds[0 * C_ + c], v, a0);
        a1 = fmaf(wlds[1 * C_ + c], v, a1);
        a2 = fmaf(wlds[2 * C_ + c], v, a2);
        a3 = fmaf(wlds[3 * C_ + c], v, a3);
    }

    red[(size_t)og * NPIX_ + p] = make_float4(a0, a1, a2, a3);   // coalesced 16B/lane

    // per-channel stats: shuffle reduce over the 64-lane wave, 1 atomic/channel/wave
    const int lane = tid & 63;
    float s0 = a0, s1 = a1, s2 = a2, s3 = a3;
    float q0 = a0*a0, q1 = a1*a1, q2 = a2*a2, q3 = a3*a3;
#pragma unroll
    for (int off = 32; off > 0; off >>= 1) {
        s0 += __shfl_down(s0, off);  q0 += __shfl_down(q0, off);
        s1 += __shfl_down(s1, off);  q1 += __shfl_down(q1, off);
        s2 += __shfl_down(s2, off);  q2 += __shfl_down(q2, off);
        s3 += __shfl_down(s3, off);  q3 += __shfl_down(q3, off);
    }
    if (lane == 0) {
        atomicAdd(&gsum[og*4+0], s0);  atomicAdd(&gsq[og*4+0], q0);
        atomicAdd(&gsum[og*4+1], s1);  atomicAdd(&gsq[og*4+1], q1);
        atomicAdd(&gsum[og*4+2], s2);  atomicAdd(&gsq[og*4+2], q2);
        atomicAdd(&gsum[og*4+3], s3);  atomicAdd(&gsq[og*4+3], q3);
    }
}

// ---------------- kernel 2: fold BN stats into scale/shift ----------------
__global__ void k_bn(const float* __restrict__ gsum, const float* __restrict__ gsq,
                     const float* __restrict__ gamma, const float* __restrict__ beta,
                     float* __restrict__ scale, float* __restrict__ shift) {
    const int o = threadIdx.x;
    if (o >= RED_) return;
    const float m   = gsum[o] * (1.0f / NSTAT_);
    const float var = gsq[o] * (1.0f / NSTAT_) - m * m;
    const float inv = rsqrtf(var + BN_EPS_);
    const float sc  = gamma[o] * inv;
    scale[o] = sc;
    shift[o] = beta[o] - m * sc;
}

// ---------------- kernel 3: act = relu(BN(red)); ker = w_span @ act + b_span ------
// grid: (64, 7); block 256. blockIdx.x -> 256 pixels, blockIdx.y -> 28 outputs.
__global__ __launch_bounds__(256) void k_span(const float4* __restrict__ red,
                                              const float* __restrict__ wspan,
                                              const float* __restrict__ bspan,
                                              const float* __restrict__ scale,
                                              const float* __restrict__ shift,
                                              float* __restrict__ ker) {
    __shared__ float wlds[OCH_ * RED_];   // 28x32 = 3.5 KiB
    __shared__ float sc_l[RED_], sh_l[RED_], bs_l[OCH_];
    const int tid   = threadIdx.x;
    const int chunk = blockIdx.y;         // 0..6
    const int obase = chunk * OCH_;
    for (int i = tid; i < OCH_ * RED_; i += 256) wlds[i] = wspan[obase * RED_ + i];
    if (tid < RED_)  { sc_l[tid] = scale[tid]; sh_l[tid] = shift[tid]; }
    if (tid < OCH_)  bs_l[tid] = bspan[obase + tid];
    __syncthreads();

    const int p  = blockIdx.x * 256 + tid;
    const int b  = p >> 12;
    const int hw = p & 4095;

    float act[RED_];
#pragma unroll
    for (int og = 0; og < 8; ++og) {
        const float4 v = red[(size_t)og * NPIX_ + p];
        act[4*og+0] = v.x; act[4*og+1] = v.y; act[4*og+2] = v.z; act[4*og+3] = v.w;
    }
#pragma unroll
    for (int o = 0; o < RED_; ++o)
        act[o] = fmaxf(fmaf(act[o], sc_l[o], sh_l[o]), 0.0f);

    float* kp = ker + ((size_t)b * KKG_ + obase) * HW_ + hw;
#pragma unroll 4
    for (int o = 0; o < OCH_; ++o) {
        float s = bs_l[o];
#pragma unroll
        for (int c = 0; c < RED_; ++c)
            s = fmaf(wlds[o * RED_ + c], act[c], s);   // LDS broadcast
        kp[(size_t)o * HW_] = s;                       // coalesced across wave
    }
}

// ---------------- kernel 4: involution ----------------
// thread per output element, idx over [B][C][H][W]
__global__ __launch_bounds__(256) void k_inv(const float* __restrict__ x,
                                             const float* __restrict__ ker,
                                             float* __restrict__ out) {
    const int idx = blockIdx.x * 256 + threadIdx.x;
    const int w = idx & 63;
    const int h = (idx >> 6) & 63;
    const int c = (idx >> 12) & 255;
    const int b = idx >> 20;
    const int g = c >> 6;

    const float* kp = ker + ((size_t)b * KKG_ + g * KK_) * HW_ + h * 64 + w;
    const float* xp = x + ((size_t)b * C_ + c) * HW_;

    float s = 0.0f;
#pragma unroll
    for (int i = 0; i < K_; ++i) {
        const int hh = h + i - P_;
        if (hh < 0 || hh >= H_) continue;
#pragma unroll
        for (int j = 0; j < K_; ++j) {
            const int ww = w + j - P_;
            if (ww < 0 || ww >= W_) continue;
            s = fmaf(kp[(i * K_ + j) * HW_], xp[hh * 64 + ww], s);
        }
    }
    out[idx] = s;
}

extern "C" void kernel_launch(void* const* d_in, const int* in_sizes, int n_in,
                              void* d_out, int out_size, void* d_ws, size_t ws_size,
                              hipStream_t stream) {
    const float* x     = (const float*)d_in[0];
    const float* wr    = (const float*)d_in[1];
    const float* gamma = (const float*)d_in[2];
    const float* beta  = (const float*)d_in[3];
    const float* wspan = (const float*)d_in[4];
    const float* bspan = (const float*)d_in[5];
    float* out = (float*)d_out;
    float* ws  = (float*)d_ws;

    // workspace layout (floats)
    float* red   = ws;                    // [8][16384] float4 = 524288 floats
    float* gsum  = ws + 524288;           // 32
    float* gsq   = gsum + 32;             // 32
    float* scale = gsq + 32;              // 32
    float* shift = scale + 32;            // 32
    float* ker   = shift + 32;            // 4*196*4096 = 3211264 floats

    hipLaunchKernelGGL(k_zero,   dim3(1),          dim3(64),  0, stream, gsum);
    hipLaunchKernelGGL(k_reduce, dim3(64, 8),      dim3(256), 0, stream, x, wr, (float4*)red, gsum, gsq);
    hipLaunchKernelGGL(k_bn,     dim3(1),          dim3(32),  0, stream, gsum, gsq, gamma, beta, scale, shift);
    hipLaunchKernelGGL(k_span,   dim3(64, 7),      dim3(256), 0, stream, (const float4*)red, wspan, bspan, scale, shift, ker);
    hipLaunchKernelGGL(k_inv,    dim3(16384),      dim3(256), 0, stream, x, ker, out);
}

// Round 3
// 168.114 us; speedup vs baseline: 1.9557x; 1.5079x over previous
//
#include <hip/hip_runtime.h>

#define B_ 4
#define C_ 256
#define H_ 64
#define W_ 64
#define HW_ 4096
#define G_ 4
#define K_ 7
#define P_ 3
#define KK_ 49
#define KKG_ 196
#define RED_ 32
#define NPIX_ 16384          // B*HW
#define NSTAT_ 16384.0f
#define BN_EPS_ 1e-5f
#define OCH_ 28              // k_span outputs per chunk (196 = 7*28)
#define CSPLIT_ 4            // k_reduce c-chunks

// ---------------- kernel 0: zero the stats accumulators ----------------
__global__ void k_zero(float* g) {
    if (threadIdx.x < 64) g[threadIdx.x] = 0.0f;
}

// ---------------- kernel 1: partial red = w_reduce @ x ----------------
// grid (16, 8, 4); block 256. Thread = 4 consecutive pixels (float4).
// bx -> 1024 pixels, by=og (4 o-ch), bz = c-chunk (64 c).
// part layout: [bz][og][p] float4
__global__ __launch_bounds__(256) void k_reduce(const float* __restrict__ x,
                                               const float* __restrict__ wr,
                                               float4* __restrict__ part) {
    __shared__ float wlds[4 * 64];      // 4 o-rows x 64 c
    const int tid = threadIdx.x;
    const int og  = blockIdx.y;
    const int bz  = blockIdx.z;
    if (tid < 256) {
        // wlds[oi][cc] = wr[(og*4+oi)*256 + bz*64 + cc]
        if (tid < 4 * 64) {
            const int oi = tid >> 6, cc = tid & 63;
            wlds[tid] = wr[(og * 4 + oi) * C_ + bz * 64 + cc];
        }
    }
    __syncthreads();

    const int p4 = blockIdx.x * 256 + tid;    // pixel-quad id, 0..4095
    const int b  = p4 >> 10;
    const int hw = (p4 & 1023) << 2;
    const float* xp = x + ((size_t)(b * C_ + bz * 64)) * HW_ + hw;

    float a[4][4];
#pragma unroll
    for (int oi = 0; oi < 4; ++oi)
#pragma unroll
        for (int q = 0; q < 4; ++q) a[oi][q] = 0.0f;

#pragma unroll 8
    for (int cc = 0; cc < 64; ++cc) {
        const float4 v = *(const float4*)(xp + (size_t)cc * HW_);
#pragma unroll
        for (int oi = 0; oi < 4; ++oi) {
            const float wv = wlds[oi * 64 + cc];
            a[oi][0] = fmaf(wv, v.x, a[oi][0]);
            a[oi][1] = fmaf(wv, v.y, a[oi][1]);
            a[oi][2] = fmaf(wv, v.z, a[oi][2]);
            a[oi][3] = fmaf(wv, v.w, a[oi][3]);
        }
    }

    // part[(bz*8+og)][4*p4+q] = (a[0][q],a[1][q],a[2][q],a[3][q])
    float4* pp = part + (((size_t)(bz * 8 + og)) << 14) + (p4 << 2);
#pragma unroll
    for (int q = 0; q < 4; ++q)
        pp[q] = make_float4(a[0][q], a[1][q], a[2][q], a[3][q]);
}

// ---------------- kernel 1b: combine partials, write red, BN stats ----------------
// grid 64 x 256; thread = one pixel
__global__ __launch_bounds__(256) void k_comb(const float4* __restrict__ part,
                                              float4* __restrict__ red,
                                              float* __restrict__ gsum,
                                              float* __restrict__ gsq) {
    const int p = blockIdx.x * 256 + threadIdx.x;   // 0..16383
    const int lane = threadIdx.x & 63;

#pragma unroll
    for (int og = 0; og < 8; ++og) {
        float4 s = make_float4(0.f, 0.f, 0.f, 0.f);
#pragma unroll
        for (int bz = 0; bz < CSPLIT_; ++bz) {
            const float4 v = part[(((size_t)(bz * 8 + og)) << 14) + p];
            s.x += v.x; s.y += v.y; s.z += v.z; s.w += v.w;
        }
        red[((size_t)og << 14) + p] = s;

        float s0 = s.x, s1 = s.y, s2 = s.z, s3 = s.w;
        float q0 = s.x*s.x, q1 = s.y*s.y, q2 = s.z*s.z, q3 = s.w*s.w;
#pragma unroll
        for (int off = 32; off > 0; off >>= 1) {
            s0 += __shfl_down(s0, off);  q0 += __shfl_down(q0, off);
            s1 += __shfl_down(s1, off);  q1 += __shfl_down(q1, off);
            s2 += __shfl_down(s2, off);  q2 += __shfl_down(q2, off);
            s3 += __shfl_down(s3, off);  q3 += __shfl_down(q3, off);
        }
        if (lane == 0) {
            atomicAdd(&gsum[og*4+0], s0);  atomicAdd(&gsq[og*4+0], q0);
            atomicAdd(&gsum[og*4+1], s1);  atomicAdd(&gsq[og*4+1], q1);
            atomicAdd(&gsum[og*4+2], s2);  atomicAdd(&gsq[og*4+2], q2);
            atomicAdd(&gsum[og*4+3], s3);  atomicAdd(&gsq[og*4+3], q3);
        }
    }
}

// ---------------- kernel 2: fold BN stats into scale/shift ----------------
__global__ void k_bn(const float* __restrict__ gsum, const float* __restrict__ gsq,
                     const float* __restrict__ gamma, const float* __restrict__ beta,
                     float* __restrict__ scale, float* __restrict__ shift) {
    const int o = threadIdx.x;
    if (o >= RED_) return;
    const float m   = gsum[o] * (1.0f / NSTAT_);
    const float var = gsq[o] * (1.0f / NSTAT_) - m * m;
    const float inv = rsqrtf(var + BN_EPS_);
    const float sc  = gamma[o] * inv;
    scale[o] = sc;
    shift[o] = beta[o] - m * sc;
}

// ---------------- kernel 3: act = relu(BN(red)); ker = w_span @ act + b_span ------
// grid: (64, 7); block 256. blockIdx.x -> 256 pixels, blockIdx.y -> 28 outputs.
__global__ __launch_bounds__(256) void k_span(const float4* __restrict__ red,
                                              const float* __restrict__ wspan,
                                              const float* __restrict__ bspan,
                                              const float* __restrict__ scale,
                                              const float* __restrict__ shift,
                                              float* __restrict__ ker) {
    __shared__ float wlds[OCH_ * RED_];   // 28x32 = 3.5 KiB
    __shared__ float sc_l[RED_], sh_l[RED_], bs_l[OCH_];
    const int tid   = threadIdx.x;
    const int chunk = blockIdx.y;         // 0..6
    const int obase = chunk * OCH_;
    for (int i = tid; i < OCH_ * RED_; i += 256) wlds[i] = wspan[obase * RED_ + i];
    if (tid < RED_)  { sc_l[tid] = scale[tid]; sh_l[tid] = shift[tid]; }
    if (tid < OCH_)  bs_l[tid] = bspan[obase + tid];
    __syncthreads();

    const int p  = blockIdx.x * 256 + tid;
    const int b  = p >> 12;
    const int hw = p & 4095;

    float act[RED_];
#pragma unroll
    for (int og = 0; og < 8; ++og) {
        const float4 v = red[((size_t)og << 14) + p];
        act[4*og+0] = v.x; act[4*og+1] = v.y; act[4*og+2] = v.z; act[4*og+3] = v.w;
    }
#pragma unroll
    for (int o = 0; o < RED_; ++o)
        act[o] = fmaxf(fmaf(act[o], sc_l[o], sh_l[o]), 0.0f);

    float* kp = ker + ((size_t)b * KKG_ + obase) * HW_ + hw;
#pragma unroll 4
    for (int o = 0; o < OCH_; ++o) {
        float s = bs_l[o];
#pragma unroll
        for (int c = 0; c < RED_; ++c)
            s = fmaf(wlds[o * RED_ + c], act[c], s);   // LDS broadcast
        kp[(size_t)o * HW_] = s;                       // coalesced across wave
    }
}

// ---------------- kernel 4: involution, register-blocked 4c x 4w ----------------
// grid 1024; block 256. bx = b*256 + cblk*4 + h4; tid = (hq<<4)|w4.
// Thread computes outputs (c0..c0+3) x (h) x (w0..w0+3).
__global__ __launch_bounds__(256) void k_inv(const float* __restrict__ x,
                                             const float* __restrict__ ker,
                                             float* __restrict__ out) {
    const int tid = threadIdx.x;
    const int w4  = tid & 15;
    const int w0  = w4 << 2;
    const int bx  = blockIdx.x;
    const int h   = ((bx & 3) << 4) + (tid >> 4);
    const int cblk = (bx >> 2) & 63;
    const int b   = bx >> 8;
    const int c0  = cblk << 2;
    const int g   = c0 >> 6;

    const float* kp  = ker + (((size_t)b * KKG_ + g * KK_) << 12) + (h << 6) + w0;
    const float* xp0 = x + (((size_t)b * C_ + c0) << 12);

    float4 acc[4];
#pragma unroll
    for (int ci = 0; ci < 4; ++ci) acc[ci] = make_float4(0.f, 0.f, 0.f, 0.f);

#pragma unroll
    for (int i = 0; i < K_; ++i) {
        const int hh = h + i - P_;
        if (hh < 0 || hh >= H_) continue;

        float win[4][12];
#pragma unroll
        for (int ci = 0; ci < 4; ++ci) {
            const float* row = xp0 + ((size_t)ci << 12) + (hh << 6);
            float4 L = make_float4(0.f,0.f,0.f,0.f);
            float4 R = make_float4(0.f,0.f,0.f,0.f);
            if (w4 > 0)  L = *(const float4*)(row + w0 - 4);
            const float4 M = *(const float4*)(row + w0);
            if (w4 < 15) R = *(const float4*)(row + w0 + 4);
            win[ci][0]=L.x; win[ci][1]=L.y; win[ci][2]=L.z; win[ci][3]=L.w;
            win[ci][4]=M.x; win[ci][5]=M.y; win[ci][6]=M.z; win[ci][7]=M.w;
            win[ci][8]=R.x; win[ci][9]=R.y; win[ci][10]=R.z; win[ci][11]=R.w;
        }

#pragma unroll
        for (int j = 0; j < K_; ++j) {
            const float4 kv = *(const float4*)(kp + (size_t)((i * K_ + j) << 12));
#pragma unroll
            for (int ci = 0; ci < 4; ++ci) {
                acc[ci].x = fmaf(kv.x, win[ci][j + 1], acc[ci].x);
                acc[ci].y = fmaf(kv.y, win[ci][j + 2], acc[ci].y);
                acc[ci].z = fmaf(kv.z, win[ci][j + 3], acc[ci].z);
                acc[ci].w = fmaf(kv.w, win[ci][j + 4], acc[ci].w);
            }
        }
    }

#pragma unroll
    for (int ci = 0; ci < 4; ++ci)
        *(float4*)(out + (((size_t)b * C_ + c0 + ci) << 12) + (h << 6) + w0) = acc[ci];
}

extern "C" void kernel_launch(void* const* d_in, const int* in_sizes, int n_in,
                              void* d_out, int out_size, void* d_ws, size_t ws_size,
                              hipStream_t stream) {
    const float* x     = (const float*)d_in[0];
    const float* wr    = (const float*)d_in[1];
    const float* gamma = (const float*)d_in[2];
    const float* beta  = (const float*)d_in[3];
    const float* wspan = (const float*)d_in[4];
    const float* bspan = (const float*)d_in[5];
    float* out = (float*)d_out;
    float* ws  = (float*)d_ws;

    // workspace layout (floats)
    float* red   = ws;                    // [8][16384] float4 = 524288 floats
    float* gsum  = ws + 524288;           // 32
    float* gsq   = gsum + 32;             // 32
    float* scale = gsq + 32;              // 32
    float* shift = scale + 32;            // 32
    float* ker   = ws + 524416;           // 4*196*4096 = 3211264 floats (16B aligned)
    float* part  = ker;                   // [4][8][16384] float4 = 2097152 floats, aliased
                                          // (consumed by k_comb before k_span writes ker)

    hipLaunchKernelGGL(k_zero,   dim3(1),         dim3(64),  0, stream, gsum);
    hipLaunchKernelGGL(k_reduce, dim3(16, 8, 4),  dim3(256), 0, stream, x, wr, (float4*)part);
    hipLaunchKernelGGL(k_comb,   dim3(64),        dim3(256), 0, stream, (const float4*)part, (float4*)red, gsum, gsq);
    hipLaunchKernelGGL(k_bn,     dim3(1),         dim3(32),  0, stream, gsum, gsq, gamma, beta, scale, shift);
    hipLaunchKernelGGL(k_span,   dim3(64, 7),     dim3(256), 0, stream, (const float4*)red, wspan, bspan, scale, shift, ker);
    hipLaunchKernelGGL(k_inv,    dim3(1024),      dim3(256), 0, stream, x, ker, out);
}

// Round 4
// 71.895 us; speedup vs baseline: 4.5730x; 2.3383x over previous
//
#include <hip/hip_runtime.h>

#define B_ 4
#define C_ 256
#define H_ 64
#define W_ 64
#define HW_ 4096
#define G_ 4
#define K_ 7
#define P_ 3
#define KK_ 49
#define KKG_ 196
#define RED_ 32
#define NPIX_ 16384          // B*HW
#define NSTAT_ 16384.0f
#define BN_EPS_ 1e-5f
#define OCH_ 28              // k_span outputs per chunk (196 = 7*28)
#define CSPLIT_ 4            // k_reduce c-chunks

// ---------------- kernel 0: zero the stats accumulators ----------------
__global__ void k_zero(float* g) {
    if (threadIdx.x < 64) g[threadIdx.x] = 0.0f;
}

// ---------------- kernel 1: partial red = w_reduce @ x ----------------
// grid (16, 8, 4); block 256. Thread = 4 consecutive pixels (float4).
// bx -> 1024 pixels, by=og (4 o-ch), bz = c-chunk (64 c).
// part layout: [bz][og][p] float4
__global__ __launch_bounds__(256) void k_reduce(const float* __restrict__ x,
                                               const float* __restrict__ wr,
                                               float4* __restrict__ part) {
    __shared__ float wlds[4 * 64];      // 4 o-rows x 64 c
    const int tid = threadIdx.x;
    const int og  = blockIdx.y;
    const int bz  = blockIdx.z;
    if (tid < 4 * 64) {
        const int oi = tid >> 6, cc = tid & 63;
        wlds[tid] = wr[(og * 4 + oi) * C_ + bz * 64 + cc];
    }
    __syncthreads();

    const int p4 = blockIdx.x * 256 + tid;    // pixel-quad id, 0..4095
    const int b  = p4 >> 10;
    const int hw = (p4 & 1023) << 2;
    const float* xp = x + ((size_t)(b * C_ + bz * 64)) * HW_ + hw;

    float a[4][4];
#pragma unroll
    for (int oi = 0; oi < 4; ++oi)
#pragma unroll
        for (int q = 0; q < 4; ++q) a[oi][q] = 0.0f;

#pragma unroll 8
    for (int cc = 0; cc < 64; ++cc) {
        const float4 v = *(const float4*)(xp + (size_t)cc * HW_);
#pragma unroll
        for (int oi = 0; oi < 4; ++oi) {
            const float wv = wlds[oi * 64 + cc];
            a[oi][0] = fmaf(wv, v.x, a[oi][0]);
            a[oi][1] = fmaf(wv, v.y, a[oi][1]);
            a[oi][2] = fmaf(wv, v.z, a[oi][2]);
            a[oi][3] = fmaf(wv, v.w, a[oi][3]);
        }
    }

    // part[(bz*8+og)][4*p4+q] = (a[0][q],a[1][q],a[2][q],a[3][q])
    float4* pp = part + (((size_t)(bz * 8 + og)) << 14) + (p4 << 2);
#pragma unroll
    for (int q = 0; q < 4; ++q)
        pp[q] = make_float4(a[0][q], a[1][q], a[2][q], a[3][q]);
}

// ---------------- kernel 1b: combine partials, write red, BN stats ----------------
// grid (64, 8); block 256. bx -> 256 pixels, by = og. Thread = one pixel, one og.
__global__ __launch_bounds__(256) void k_comb(const float4* __restrict__ part,
                                              float4* __restrict__ red,
                                              float* __restrict__ gsum,
                                              float* __restrict__ gsq) {
    __shared__ float lsum[4][8];   // [wave][4 sum + 4 sq]
    const int tid  = threadIdx.x;
    const int lane = tid & 63;
    const int wv   = tid >> 6;
    const int og   = blockIdx.y;
    const int p    = blockIdx.x * 256 + tid;   // 0..16383

    float4 s = make_float4(0.f, 0.f, 0.f, 0.f);
#pragma unroll
    for (int bz = 0; bz < CSPLIT_; ++bz) {
        const float4 v = part[(((size_t)(bz * 8 + og)) << 14) + p];
        s.x += v.x; s.y += v.y; s.z += v.z; s.w += v.w;
    }
    red[((size_t)og << 14) + p] = s;

    float s0 = s.x, s1 = s.y, s2 = s.z, s3 = s.w;
    float q0 = s.x*s.x, q1 = s.y*s.y, q2 = s.z*s.z, q3 = s.w*s.w;
#pragma unroll
    for (int off = 32; off > 0; off >>= 1) {
        s0 += __shfl_down(s0, off);  q0 += __shfl_down(q0, off);
        s1 += __shfl_down(s1, off);  q1 += __shfl_down(q1, off);
        s2 += __shfl_down(s2, off);  q2 += __shfl_down(q2, off);
        s3 += __shfl_down(s3, off);  q3 += __shfl_down(q3, off);
    }
    if (lane == 0) {
        lsum[wv][0] = s0; lsum[wv][1] = s1; lsum[wv][2] = s2; lsum[wv][3] = s3;
        lsum[wv][4] = q0; lsum[wv][5] = q1; lsum[wv][6] = q2; lsum[wv][7] = q3;
    }
    __syncthreads();
    if (tid < 8) {
        const float v = lsum[0][tid] + lsum[1][tid] + lsum[2][tid] + lsum[3][tid];
        float* dst = (tid < 4) ? &gsum[og * 4 + tid] : &gsq[og * 4 + (tid - 4)];
        atomicAdd(dst, v);
    }
}

// ---------------- kernel 2: fold BN stats into scale/shift ----------------
__global__ void k_bn(const float* __restrict__ gsum, const float* __restrict__ gsq,
                     const float* __restrict__ gamma, const float* __restrict__ beta,
                     float* __restrict__ scale, float* __restrict__ shift) {
    const int o = threadIdx.x;
    if (o >= RED_) return;
    const float m   = gsum[o] * (1.0f / NSTAT_);
    const float var = gsq[o] * (1.0f / NSTAT_) - m * m;
    const float inv = rsqrtf(var + BN_EPS_);
    const float sc  = gamma[o] * inv;
    scale[o] = sc;
    shift[o] = beta[o] - m * sc;
}

// ---------------- kernel 3: act = relu(BN(red)); ker = w_span @ act + b_span ------
// grid: (64, 7); block 256. blockIdx.x -> 256 pixels, blockIdx.y -> 28 outputs.
__global__ __launch_bounds__(256) void k_span(const float4* __restrict__ red,
                                              const float* __restrict__ wspan,
                                              const float* __restrict__ bspan,
                                              const float* __restrict__ scale,
                                              const float* __restrict__ shift,
                                              float* __restrict__ ker) {
    __shared__ float wlds[OCH_ * RED_];   // 28x32 = 3.5 KiB
    __shared__ float sc_l[RED_], sh_l[RED_], bs_l[OCH_];
    const int tid   = threadIdx.x;
    const int chunk = blockIdx.y;         // 0..6
    const int obase = chunk * OCH_;
    for (int i = tid; i < OCH_ * RED_; i += 256) wlds[i] = wspan[obase * RED_ + i];
    if (tid < RED_)  { sc_l[tid] = scale[tid]; sh_l[tid] = shift[tid]; }
    if (tid < OCH_)  bs_l[tid] = bspan[obase + tid];
    __syncthreads();

    const int p  = blockIdx.x * 256 + tid;
    const int b  = p >> 12;
    const int hw = p & 4095;

    float act[RED_];
#pragma unroll
    for (int og = 0; og < 8; ++og) {
        const float4 v = red[((size_t)og << 14) + p];
        act[4*og+0] = v.x; act[4*og+1] = v.y; act[4*og+2] = v.z; act[4*og+3] = v.w;
    }
#pragma unroll
    for (int o = 0; o < RED_; ++o)
        act[o] = fmaxf(fmaf(act[o], sc_l[o], sh_l[o]), 0.0f);

    float* kp = ker + ((size_t)b * KKG_ + obase) * HW_ + hw;
#pragma unroll 4
    for (int o = 0; o < OCH_; ++o) {
        float s = bs_l[o];
#pragma unroll
        for (int c = 0; c < RED_; ++c)
            s = fmaf(wlds[o * RED_ + c], act[c], s);   // LDS broadcast
        kp[(size_t)o * HW_] = s;                       // coalesced across wave
    }
}

// ---------------- kernel 4: involution, register-blocked 4c x 4w ----------------
// grid 1024; block 256. bx = b*256 + cblk*4 + h4; tid = (hq<<4)|w4.
// Thread computes outputs (c0..c0+3) x (h) x (w0..w0+3).
__global__ __launch_bounds__(256) void k_inv(const float* __restrict__ x,
                                             const float* __restrict__ ker,
                                             float* __restrict__ out) {
    const int tid = threadIdx.x;
    const int w4  = tid & 15;
    const int w0  = w4 << 2;
    const int bx  = blockIdx.x;
    const int h   = ((bx & 3) << 4) + (tid >> 4);
    const int cblk = (bx >> 2) & 63;
    const int b   = bx >> 8;
    const int c0  = cblk << 2;
    const int g   = c0 >> 6;

    const float* kp  = ker + (((size_t)b * KKG_ + g * KK_) << 12) + (h << 6) + w0;
    const float* xp0 = x + (((size_t)b * C_ + c0) << 12);

    float4 acc[4];
#pragma unroll
    for (int ci = 0; ci < 4; ++ci) acc[ci] = make_float4(0.f, 0.f, 0.f, 0.f);

#pragma unroll
    for (int i = 0; i < K_; ++i) {
        const int hh = h + i - P_;
        if (hh < 0 || hh >= H_) continue;

        float win[4][12];
#pragma unroll
        for (int ci = 0; ci < 4; ++ci) {
            const float* row = xp0 + ((size_t)ci << 12) + (hh << 6);
            float4 L = make_float4(0.f,0.f,0.f,0.f);
            float4 R = make_float4(0.f,0.f,0.f,0.f);
            if (w4 > 0)  L = *(const float4*)(row + w0 - 4);
            const float4 M = *(const float4*)(row + w0);
            if (w4 < 15) R = *(const float4*)(row + w0 + 4);
            win[ci][0]=L.x; win[ci][1]=L.y; win[ci][2]=L.z; win[ci][3]=L.w;
            win[ci][4]=M.x; win[ci][5]=M.y; win[ci][6]=M.z; win[ci][7]=M.w;
            win[ci][8]=R.x; win[ci][9]=R.y; win[ci][10]=R.z; win[ci][11]=R.w;
        }

#pragma unroll
        for (int j = 0; j < K_; ++j) {
            const float4 kv = *(const float4*)(kp + (size_t)((i * K_ + j) << 12));
#pragma unroll
            for (int ci = 0; ci < 4; ++ci) {
                acc[ci].x = fmaf(kv.x, win[ci][j + 1], acc[ci].x);
                acc[ci].y = fmaf(kv.y, win[ci][j + 2], acc[ci].y);
                acc[ci].z = fmaf(kv.z, win[ci][j + 3], acc[ci].z);
                acc[ci].w = fmaf(kv.w, win[ci][j + 4], acc[ci].w);
            }
        }
    }

#pragma unroll
    for (int ci = 0; ci < 4; ++ci)
        *(float4*)(out + (((size_t)b * C_ + c0 + ci) << 12) + (h << 6) + w0) = acc[ci];
}

extern "C" void kernel_launch(void* const* d_in, const int* in_sizes, int n_in,
                              void* d_out, int out_size, void* d_ws, size_t ws_size,
                              hipStream_t stream) {
    const float* x     = (const float*)d_in[0];
    const float* wr    = (const float*)d_in[1];
    const float* gamma = (const float*)d_in[2];
    const float* beta  = (const float*)d_in[3];
    const float* wspan = (const float*)d_in[4];
    const float* bspan = (const float*)d_in[5];
    float* out = (float*)d_out;
    float* ws  = (float*)d_ws;

    // workspace layout (floats)
    float* red   = ws;                    // [8][16384] float4 = 524288 floats
    float* gsum  = ws + 524288;           // 32
    float* gsq   = gsum + 32;             // 32
    float* scale = gsq + 32;              // 32
    float* shift = scale + 32;            // 32
    float* ker   = ws + 524416;           // 4*196*4096 = 3211264 floats (16B aligned)
    float* part  = ker;                   // [4][8][16384] float4 = 2097152 floats, aliased
                                          // (consumed by k_comb before k_span writes ker)

    hipLaunchKernelGGL(k_zero,   dim3(1),         dim3(64),  0, stream, gsum);
    hipLaunchKernelGGL(k_reduce, dim3(16, 8, 4),  dim3(256), 0, stream, x, wr, (float4*)part);
    hipLaunchKernelGGL(k_comb,   dim3(64, 8),     dim3(256), 0, stream, (const float4*)part, (float4*)red, gsum, gsq);
    hipLaunchKernelGGL(k_bn,     dim3(1),         dim3(32),  0, stream, gsum, gsq, gamma, beta, scale, shift);
    hipLaunchKernelGGL(k_span,   dim3(64, 7),     dim3(256), 0, stream, (const float4*)red, wspan, bspan, scale, shift, ker);
    hipLaunchKernelGGL(k_inv,    dim3(1024),      dim3(256), 0, stream, x, ker, out);
}

// Round 5
// 68.790 us; speedup vs baseline: 4.7795x; 1.0451x over previous
//
#include <hip/hip_runtime.h>

#define B_ 4
#define C_ 256
#define H_ 64
#define W_ 64
#define HW_ 4096
#define G_ 4
#define K_ 7
#define P_ 3
#define KK_ 49
#define KKG_ 196
#define RED_ 32
#define NPIX_ 16384          // B*HW
#define NSTAT_ 16384.0f
#define BN_EPS_ 1e-5f
#define OCH_ 28              // k_span outputs per chunk (196 = 7*28)
#define CSPLIT_ 4            // k_reduce c-chunks

// k_inv tile geometry
#define TILE_H 16
#define TROWS 22             // TILE_H + 6 halo rows
#define TROW  72             // 4 pad + 64 + 4 pad (stride keeps 16B alignment)

// ---------------- kernel 0: zero the stats accumulators ----------------
__global__ void k_zero(float* g) {
    if (threadIdx.x < 64) g[threadIdx.x] = 0.0f;
}

// ---------------- kernel 1: partial red = w_reduce @ x ----------------
// grid (16, 8, 4); block 256. Thread = 4 consecutive pixels (float4).
// part layout: [bz][og][p] float4
__global__ __launch_bounds__(256) void k_reduce(const float* __restrict__ x,
                                               const float* __restrict__ wr,
                                               float4* __restrict__ part) {
    __shared__ float wlds[4 * 64];      // 4 o-rows x 64 c
    const int tid = threadIdx.x;
    const int og  = blockIdx.y;
    const int bz  = blockIdx.z;
    if (tid < 4 * 64) {
        const int oi = tid >> 6, cc = tid & 63;
        wlds[tid] = wr[(og * 4 + oi) * C_ + bz * 64 + cc];
    }
    __syncthreads();

    const int p4 = blockIdx.x * 256 + tid;    // pixel-quad id, 0..4095
    const int b  = p4 >> 10;
    const int hw = (p4 & 1023) << 2;
    const float* xp = x + ((size_t)(b * C_ + bz * 64)) * HW_ + hw;

    float a[4][4];
#pragma unroll
    for (int oi = 0; oi < 4; ++oi)
#pragma unroll
        for (int q = 0; q < 4; ++q) a[oi][q] = 0.0f;

#pragma unroll 8
    for (int cc = 0; cc < 64; ++cc) {
        const float4 v = *(const float4*)(xp + (size_t)cc * HW_);
#pragma unroll
        for (int oi = 0; oi < 4; ++oi) {
            const float wv = wlds[oi * 64 + cc];
            a[oi][0] = fmaf(wv, v.x, a[oi][0]);
            a[oi][1] = fmaf(wv, v.y, a[oi][1]);
            a[oi][2] = fmaf(wv, v.z, a[oi][2]);
            a[oi][3] = fmaf(wv, v.w, a[oi][3]);
        }
    }

    float4* pp = part + (((size_t)(bz * 8 + og)) << 14) + (p4 << 2);
#pragma unroll
    for (int q = 0; q < 4; ++q)
        pp[q] = make_float4(a[0][q], a[1][q], a[2][q], a[3][q]);
}

// ---------------- kernel 1b: combine partials, write red, BN stats ----------------
// grid (64, 8); block 256. bx -> 256 pixels, by = og.
__global__ __launch_bounds__(256) void k_comb(const float4* __restrict__ part,
                                              float4* __restrict__ red,
                                              float* __restrict__ gsum,
                                              float* __restrict__ gsq) {
    __shared__ float lsum[4][8];
    const int tid  = threadIdx.x;
    const int lane = tid & 63;
    const int wv   = tid >> 6;
    const int og   = blockIdx.y;
    const int p    = blockIdx.x * 256 + tid;

    float4 s = make_float4(0.f, 0.f, 0.f, 0.f);
#pragma unroll
    for (int bz = 0; bz < CSPLIT_; ++bz) {
        const float4 v = part[(((size_t)(bz * 8 + og)) << 14) + p];
        s.x += v.x; s.y += v.y; s.z += v.z; s.w += v.w;
    }
    red[((size_t)og << 14) + p] = s;

    float s0 = s.x, s1 = s.y, s2 = s.z, s3 = s.w;
    float q0 = s.x*s.x, q1 = s.y*s.y, q2 = s.z*s.z, q3 = s.w*s.w;
#pragma unroll
    for (int off = 32; off > 0; off >>= 1) {
        s0 += __shfl_down(s0, off);  q0 += __shfl_down(q0, off);
        s1 += __shfl_down(s1, off);  q1 += __shfl_down(q1, off);
        s2 += __shfl_down(s2, off);  q2 += __shfl_down(q2, off);
        s3 += __shfl_down(s3, off);  q3 += __shfl_down(q3, off);
    }
    if (lane == 0) {
        lsum[wv][0] = s0; lsum[wv][1] = s1; lsum[wv][2] = s2; lsum[wv][3] = s3;
        lsum[wv][4] = q0; lsum[wv][5] = q1; lsum[wv][6] = q2; lsum[wv][7] = q3;
    }
    __syncthreads();
    if (tid < 8) {
        const float v = lsum[0][tid] + lsum[1][tid] + lsum[2][tid] + lsum[3][tid];
        float* dst = (tid < 4) ? &gsum[og * 4 + tid] : &gsq[og * 4 + (tid - 4)];
        atomicAdd(dst, v);
    }
}

// ---------------- kernel 3: BN fold (inline) + act + ker = w_span @ act + b_span ----
// grid: (64, 7); block 256.
__global__ __launch_bounds__(256) void k_span(const float4* __restrict__ red,
                                              const float* __restrict__ wspan,
                                              const float* __restrict__ bspan,
                                              const float* __restrict__ gsum,
                                              const float* __restrict__ gsq,
                                              const float* __restrict__ gamma,
                                              const float* __restrict__ beta,
                                              float* __restrict__ ker) {
    __shared__ float wlds[OCH_ * RED_];
    __shared__ float sc_l[RED_], sh_l[RED_], bs_l[OCH_];
    const int tid   = threadIdx.x;
    const int chunk = blockIdx.y;
    const int obase = chunk * OCH_;
    for (int i = tid; i < OCH_ * RED_; i += 256) wlds[i] = wspan[obase * RED_ + i];
    if (tid < RED_) {
        const float m   = gsum[tid] * (1.0f / NSTAT_);
        const float var = gsq[tid] * (1.0f / NSTAT_) - m * m;
        const float inv = rsqrtf(var + BN_EPS_);
        const float sc  = gamma[tid] * inv;
        sc_l[tid] = sc;
        sh_l[tid] = beta[tid] - m * sc;
    }
    if (tid < OCH_) bs_l[tid] = bspan[obase + tid];
    __syncthreads();

    const int p  = blockIdx.x * 256 + tid;
    const int b  = p >> 12;
    const int hw = p & 4095;

    float act[RED_];
#pragma unroll
    for (int og = 0; og < 8; ++og) {
        const float4 v = red[((size_t)og << 14) + p];
        act[4*og+0] = v.x; act[4*og+1] = v.y; act[4*og+2] = v.z; act[4*og+3] = v.w;
    }
#pragma unroll
    for (int o = 0; o < RED_; ++o)
        act[o] = fmaxf(fmaf(act[o], sc_l[o], sh_l[o]), 0.0f);

    float* kp = ker + ((size_t)b * KKG_ + obase) * HW_ + hw;
#pragma unroll 4
    for (int o = 0; o < OCH_; ++o) {
        float s = bs_l[o];
#pragma unroll
        for (int c = 0; c < RED_; ++c)
            s = fmaf(wlds[o * RED_ + c], act[c], s);
        kp[(size_t)o * HW_] = s;
    }
}

// ---------------- kernel 4: involution, LDS-staged x, 4c x 4w per thread ----------
// grid 1024; block 256. bx = b*256 + cblk*4 + ht. tid = (hq<<4)|w4.
__global__ __launch_bounds__(256) void k_inv(const float* __restrict__ x,
                                             const float* __restrict__ ker,
                                             float* __restrict__ out) {
    __shared__ float tile[4][TROWS][TROW];   // ~25.3 KiB
    const int tid = threadIdx.x;
    const int w4  = tid & 15;
    const int w0  = w4 << 2;
    const int hq  = tid >> 4;           // 0..15
    const int bx  = blockIdx.x;
    const int ht  = bx & 3;
    const int h0  = ht << 4;
    const int h   = h0 + hq;
    const int cblk = (bx >> 2) & 63;
    const int b   = bx >> 8;
    const int c0  = cblk << 2;
    const int g   = c0 >> 6;

    // ---- stage x tile: interior (with OOB-row zero fill) + side pads ----
    const float4 fz = make_float4(0.f, 0.f, 0.f, 0.f);
    for (int i = tid; i < 4 * TROWS * 16; i += 256) {   // 1408 float4 writes
        const int ci  = i / (TROWS * 16);
        const int rem = i - ci * (TROWS * 16);
        const int r   = rem >> 4;
        const int seg = rem & 15;
        const int hh  = h0 + r - P_;
        float4 v = fz;
        if (hh >= 0 && hh < H_)
            v = *(const float4*)(x + (((size_t)(b * C_ + c0 + ci)) << 12) + (hh << 6) + (seg << 2));
        *(float4*)&tile[ci][r][4 + (seg << 2)] = v;
    }
    if (tid < 4 * TROWS * 2) {          // 176 pad writes (left+right 4-float pads)
        const int ci   = tid / (TROWS * 2);
        const int rem  = tid - ci * (TROWS * 2);
        const int r    = rem >> 1;
        const int side = rem & 1;
        *(float4*)&tile[ci][r][side ? (4 + W_) : 0] = fz;
    }
    __syncthreads();

    const float* kp = ker + (((size_t)b * KKG_ + g * KK_) << 12) + (h << 6) + w0;

    float4 acc[4];
#pragma unroll
    for (int ci = 0; ci < 4; ++ci) acc[ci] = fz;

#pragma unroll
    for (int i = 0; i < K_; ++i) {
        const int r = hq + i;           // tile row for input row h+i-3
        float win[4][12];
#pragma unroll
        for (int ci = 0; ci < 4; ++ci) {
            const float4 a0 = *(const float4*)&tile[ci][r][w0];
            const float4 a1 = *(const float4*)&tile[ci][r][w0 + 4];
            const float4 a2 = *(const float4*)&tile[ci][r][w0 + 8];
            win[ci][0]=a0.x; win[ci][1]=a0.y; win[ci][2] =a0.z; win[ci][3] =a0.w;
            win[ci][4]=a1.x; win[ci][5]=a1.y; win[ci][6] =a1.z; win[ci][7] =a1.w;
            win[ci][8]=a2.x; win[ci][9]=a2.y; win[ci][10]=a2.z; win[ci][11]=a2.w;
        }
#pragma unroll
        for (int j = 0; j < K_; ++j) {
            const float4 kv = *(const float4*)(kp + (size_t)((i * K_ + j) << 12));
#pragma unroll
            for (int ci = 0; ci < 4; ++ci) {
                acc[ci].x = fmaf(kv.x, win[ci][j + 1], acc[ci].x);
                acc[ci].y = fmaf(kv.y, win[ci][j + 2], acc[ci].y);
                acc[ci].z = fmaf(kv.z, win[ci][j + 3], acc[ci].z);
                acc[ci].w = fmaf(kv.w, win[ci][j + 4], acc[ci].w);
            }
        }
    }

#pragma unroll
    for (int ci = 0; ci < 4; ++ci)
        *(float4*)(out + (((size_t)b * C_ + c0 + ci) << 12) + (h << 6) + w0) = acc[ci];
}

extern "C" void kernel_launch(void* const* d_in, const int* in_sizes, int n_in,
                              void* d_out, int out_size, void* d_ws, size_t ws_size,
                              hipStream_t stream) {
    const float* x     = (const float*)d_in[0];
    const float* wr    = (const float*)d_in[1];
    const float* gamma = (const float*)d_in[2];
    const float* beta  = (const float*)d_in[3];
    const float* wspan = (const float*)d_in[4];
    const float* bspan = (const float*)d_in[5];
    float* out = (float*)d_out;
    float* ws  = (float*)d_ws;

    // workspace layout (floats)
    float* red   = ws;                    // [8][16384] float4 = 524288 floats
    float* gsum  = ws + 524288;           // 32
    float* gsq   = gsum + 32;             // 32
    float* ker   = ws + 524416;           // 4*196*4096 = 3211264 floats
    float* part  = ker;                   // [4][8][16384] float4, aliased (consumed before ker written)

    hipLaunchKernelGGL(k_zero,   dim3(1),         dim3(64),  0, stream, gsum);
    hipLaunchKernelGGL(k_reduce, dim3(16, 8, 4),  dim3(256), 0, stream, x, wr, (float4*)part);
    hipLaunchKernelGGL(k_comb,   dim3(64, 8),     dim3(256), 0, stream, (const float4*)part, (float4*)red, gsum, gsq);
    hipLaunchKernelGGL(k_span,   dim3(64, 7),     dim3(256), 0, stream, (const float4*)red, wspan, bspan, gsum, gsq, gamma, beta, ker);
    hipLaunchKernelGGL(k_inv,    dim3(1024),      dim3(256), 0, stream, x, ker, out);
}

// Round 6
// 63.343 us; speedup vs baseline: 5.1905x; 1.0860x over previous
//
#include <hip/hip_runtime.h>

#define B_ 4
#define C_ 256
#define H_ 64
#define W_ 64
#define HW_ 4096
#define G_ 4
#define K_ 7
#define P_ 3
#define KK_ 49
#define KKG_ 196
#define RED_ 32
#define NPIX_ 16384          // B*HW
#define NSTAT_ 16384.0f
#define BN_EPS_ 1e-5f
#define OCH_ 28              // k_span outputs per chunk (196 = 7*28)

// k_inv tile geometry
#define CPB_ 8               // channels per block
#define TH_ 8                // output rows per block
#define TRS_ 14              // TH_ + 6 halo rows
#define TRW_ 76              // 4 pad + 64 + 4 pad + 4 bank-skew

// ---------------- kernel 1: partial red = w_reduce @ x ----------------
// grid (32, 4, 4); block 256. Thread = 2 consecutive pixels (float2).
// by = og (8 o-channels), bz = c-chunk (64 c).
// part layout: float4 slots [(bz*4+og)*2 + half][pixel]
__global__ __launch_bounds__(256) void k_reduce(const float* __restrict__ x,
                                               const float* __restrict__ wr,
                                               float4* __restrict__ part,
                                               float* __restrict__ gstats) {
    __shared__ float wlds[8 * 64];      // 8 o-rows x 64 c
    const int tid = threadIdx.x;
    const int og  = blockIdx.y;         // 0..3
    const int bz  = blockIdx.z;         // 0..3
    if (blockIdx.x == 0 && og == 0 && bz == 0 && tid < 64) gstats[tid] = 0.0f;
    for (int i = tid; i < 512; i += 256) {
        const int oi = i >> 6, cc = i & 63;
        wlds[i] = wr[(og * 8 + oi) * C_ + bz * 64 + cc];
    }
    __syncthreads();

    const int p2 = blockIdx.x * 256 + tid;    // pixel-pair id, 0..8191
    const int b  = p2 >> 11;
    const int hw = (p2 & 2047) << 1;
    const float* xp = x + ((size_t)(b * C_ + bz * 64)) * HW_ + hw;

    float a[8][2];
#pragma unroll
    for (int oi = 0; oi < 8; ++oi) { a[oi][0] = 0.f; a[oi][1] = 0.f; }

#pragma unroll 8
    for (int cc = 0; cc < 64; ++cc) {
        const float2 v = *(const float2*)(xp + (size_t)cc * HW_);
#pragma unroll
        for (int oi = 0; oi < 8; ++oi) {
            const float wv = wlds[oi * 64 + cc];
            a[oi][0] = fmaf(wv, v.x, a[oi][0]);
            a[oi][1] = fmaf(wv, v.y, a[oi][1]);
        }
    }

    const int slot = bz * 4 + og;
    float4* pp0 = part + (((size_t)(slot * 2 + 0)) << 14) + (p2 << 1);
    float4* pp1 = part + (((size_t)(slot * 2 + 1)) << 14) + (p2 << 1);
    pp0[0] = make_float4(a[0][0], a[1][0], a[2][0], a[3][0]);
    pp0[1] = make_float4(a[0][1], a[1][1], a[2][1], a[3][1]);
    pp1[0] = make_float4(a[4][0], a[5][0], a[6][0], a[7][0]);
    pp1[1] = make_float4(a[4][1], a[5][1], a[6][1], a[7][1]);
}

// ---------------- kernel 1b: combine partials, write red, BN stats ----------------
// grid (64, 8); block 256. bx -> 256 pixels, by = oq (o-quad 0..7).
__global__ __launch_bounds__(256) void k_comb(const float4* __restrict__ part,
                                              float4* __restrict__ red,
                                              float* __restrict__ gsum,
                                              float* __restrict__ gsq) {
    __shared__ float lsum[4][8];
    const int tid  = threadIdx.x;
    const int lane = tid & 63;
    const int wv   = tid >> 6;
    const int oq   = blockIdx.y;        // 0..7
    const int og   = oq >> 1;
    const int half = oq & 1;
    const int p    = blockIdx.x * 256 + tid;

    float4 s = make_float4(0.f, 0.f, 0.f, 0.f);
#pragma unroll
    for (int bz = 0; bz < 4; ++bz) {
        const float4 v = part[(((size_t)((bz * 4 + og) * 2 + half)) << 14) + p];
        s.x += v.x; s.y += v.y; s.z += v.z; s.w += v.w;
    }
    red[((size_t)oq << 14) + p] = s;

    float s0 = s.x, s1 = s.y, s2 = s.z, s3 = s.w;
    float q0 = s.x*s.x, q1 = s.y*s.y, q2 = s.z*s.z, q3 = s.w*s.w;
#pragma unroll
    for (int off = 32; off > 0; off >>= 1) {
        s0 += __shfl_down(s0, off);  q0 += __shfl_down(q0, off);
        s1 += __shfl_down(s1, off);  q1 += __shfl_down(q1, off);
        s2 += __shfl_down(s2, off);  q2 += __shfl_down(q2, off);
        s3 += __shfl_down(s3, off);  q3 += __shfl_down(q3, off);
    }
    if (lane == 0) {
        lsum[wv][0] = s0; lsum[wv][1] = s1; lsum[wv][2] = s2; lsum[wv][3] = s3;
        lsum[wv][4] = q0; lsum[wv][5] = q1; lsum[wv][6] = q2; lsum[wv][7] = q3;
    }
    __syncthreads();
    if (tid < 8) {
        const float v = lsum[0][tid] + lsum[1][tid] + lsum[2][tid] + lsum[3][tid];
        float* dst = (tid < 4) ? &gsum[oq * 4 + tid] : &gsq[oq * 4 + (tid - 4)];
        atomicAdd(dst, v);
    }
}

// ---------------- kernel 3: BN fold (inline) + act + ker = w_span @ act + b_span ----
// grid: (64, 7); block 256.
__global__ __launch_bounds__(256) void k_span(const float4* __restrict__ red,
                                              const float* __restrict__ wspan,
                                              const float* __restrict__ bspan,
                                              const float* __restrict__ gsum,
                                              const float* __restrict__ gsq,
                                              const float* __restrict__ gamma,
                                              const float* __restrict__ beta,
                                              float* __restrict__ ker) {
    __shared__ float wlds[OCH_ * RED_];
    __shared__ float sc_l[RED_], sh_l[RED_], bs_l[OCH_];
    const int tid   = threadIdx.x;
    const int chunk = blockIdx.y;
    const int obase = chunk * OCH_;
    for (int i = tid; i < OCH_ * RED_; i += 256) wlds[i] = wspan[obase * RED_ + i];
    if (tid < RED_) {
        const float m   = gsum[tid] * (1.0f / NSTAT_);
        const float var = gsq[tid] * (1.0f / NSTAT_) - m * m;
        const float inv = rsqrtf(var + BN_EPS_);
        const float sc  = gamma[tid] * inv;
        sc_l[tid] = sc;
        sh_l[tid] = beta[tid] - m * sc;
    }
    if (tid < OCH_) bs_l[tid] = bspan[obase + tid];
    __syncthreads();

    const int p  = blockIdx.x * 256 + tid;
    const int b  = p >> 12;
    const int hw = p & 4095;

    float act[RED_];
#pragma unroll
    for (int og = 0; og < 8; ++og) {
        const float4 v = red[((size_t)og << 14) + p];
        act[4*og+0] = v.x; act[4*og+1] = v.y; act[4*og+2] = v.z; act[4*og+3] = v.w;
    }
#pragma unroll
    for (int o = 0; o < RED_; ++o)
        act[o] = fmaxf(fmaf(act[o], sc_l[o], sh_l[o]), 0.0f);

    float* kp = ker + ((size_t)b * KKG_ + obase) * HW_ + hw;
#pragma unroll 4
    for (int o = 0; o < OCH_; ++o) {
        float s = bs_l[o];
#pragma unroll
        for (int c = 0; c < RED_; ++c)
            s = fmaf(wlds[o * RED_ + c], act[c], s);
        kp[(size_t)o * HW_] = s;
    }
}

// ---------------- kernel 4: involution, 8c x 8h x 64w blocks, thread = 2c x 8w ----
// grid 1024: bx = (b<<8) | (cblk<<3) | ht.  tid = (cq<<6)|(hq<<3)|wg.
__global__ __launch_bounds__(256) void k_inv(const float* __restrict__ x,
                                             const float* __restrict__ ker,
                                             float* __restrict__ out) {
    __shared__ float tile[CPB_][TRS_][TRW_];   // 8*14*76*4 = 34048 B
    const int tid = threadIdx.x;
    const int wg  = tid & 7;            // 8-w group
    const int hq  = (tid >> 3) & 7;     // row in tile
    const int cq  = tid >> 6;           // c-pair 0..3
    const int bx  = blockIdx.x;
    const int ht  = bx & 7;
    const int cblk = (bx >> 3) & 31;
    const int b   = bx >> 8;
    const int h0  = ht << 3;
    const int c0  = cblk << 3;
    const int g   = c0 >> 6;
    const int w0  = wg << 3;
    const int h   = h0 + hq;

    const float4 fz = make_float4(0.f, 0.f, 0.f, 0.f);
    // interior: 8c * 14r * 16 float4-segments = 1792 writes, 7 per thread
#pragma unroll
    for (int it = 0; it < 7; ++it) {
        const int i   = it * 256 + tid;
        const int ci  = i / (TRS_ * 16);
        const int rem = i - ci * (TRS_ * 16);
        const int r   = rem >> 4;
        const int seg = rem & 15;
        const int hh  = h0 + r - P_;
        float4 v = fz;
        if (hh >= 0 && hh < H_)
            v = *(const float4*)(x + (((size_t)(b * C_ + c0 + ci)) << 12) + (hh << 6) + (seg << 2));
        *(float4*)&tile[ci][r][4 + (seg << 2)] = v;
    }
    if (tid < CPB_ * TRS_ * 2) {        // side pads
        const int ci  = tid / (TRS_ * 2);
        const int rem = tid - ci * (TRS_ * 2);
        const int r   = rem >> 1;
        *(float4*)&tile[ci][r][(rem & 1) ? 68 : 0] = fz;
    }
    __syncthreads();

    const int cA = cq << 1;
    const float* kp = ker + (((size_t)b * KKG_ + g * KK_) << 12) + (h << 6) + w0;

    float accA[8], accB[8];
#pragma unroll
    for (int dw = 0; dw < 8; ++dw) { accA[dw] = 0.f; accB[dw] = 0.f; }

#pragma unroll
    for (int i = 0; i < K_; ++i) {
        const int r = hq + i;
        float wa[16], wb[16];
        const float* ta = &tile[cA][r][w0];
        const float* tb = &tile[cA + 1][r][w0];
#pragma unroll
        for (int t = 0; t < 4; ++t) {
            const float4 va = *(const float4*)(ta + (t << 2));
            const float4 vb = *(const float4*)(tb + (t << 2));
            wa[4*t+0]=va.x; wa[4*t+1]=va.y; wa[4*t+2]=va.z; wa[4*t+3]=va.w;
            wb[4*t+0]=vb.x; wb[4*t+1]=vb.y; wb[4*t+2]=vb.z; wb[4*t+3]=vb.w;
        }
#pragma unroll
        for (int j = 0; j < K_; ++j) {
            const float* kpp = kp + ((size_t)(i * K_ + j) << 12);
            const float4 k0 = *(const float4*)kpp;
            const float4 k1 = *(const float4*)(kpp + 4);
            const float kv[8] = {k0.x, k0.y, k0.z, k0.w, k1.x, k1.y, k1.z, k1.w};
#pragma unroll
            for (int dw = 0; dw < 8; ++dw) {
                accA[dw] = fmaf(kv[dw], wa[dw + j + 1], accA[dw]);
                accB[dw] = fmaf(kv[dw], wb[dw + j + 1], accB[dw]);
            }
        }
    }

    float* oA = out + (((size_t)(b * C_ + c0 + cA)) << 12) + (h << 6) + w0;
    *(float4*)(oA)     = make_float4(accA[0], accA[1], accA[2], accA[3]);
    *(float4*)(oA + 4) = make_float4(accA[4], accA[5], accA[6], accA[7]);
    float* oB = oA + HW_;
    *(float4*)(oB)     = make_float4(accB[0], accB[1], accB[2], accB[3]);
    *(float4*)(oB + 4) = make_float4(accB[4], accB[5], accB[6], accB[7]);
}

extern "C" void kernel_launch(void* const* d_in, const int* in_sizes, int n_in,
                              void* d_out, int out_size, void* d_ws, size_t ws_size,
                              hipStream_t stream) {
    const float* x     = (const float*)d_in[0];
    const float* wr    = (const float*)d_in[1];
    const float* gamma = (const float*)d_in[2];
    const float* beta  = (const float*)d_in[3];
    const float* wspan = (const float*)d_in[4];
    const float* bspan = (const float*)d_in[5];
    float* out = (float*)d_out;
    float* ws  = (float*)d_ws;

    // workspace layout (floats)
    float* red   = ws;                    // [8][16384] float4 = 524288 floats
    float* gsum  = ws + 524288;           // 32  (gstats = gsum..gsq contiguous 64)
    float* gsq   = gsum + 32;             // 32
    float* ker   = ws + 524416;           // 4*196*4096 = 3211264 floats
    float* part  = ker;                   // [32][16384] float4 = 8.4 MB, aliased
                                          // (consumed by k_comb before k_span writes ker)

    hipLaunchKernelGGL(k_reduce, dim3(32, 4, 4),  dim3(256), 0, stream, x, wr, (float4*)part, gsum);
    hipLaunchKernelGGL(k_comb,   dim3(64, 8),     dim3(256), 0, stream, (const float4*)part, (float4*)red, gsum, gsq);
    hipLaunchKernelGGL(k_span,   dim3(64, 7),     dim3(256), 0, stream, (const float4*)red, wspan, bspan, gsum, gsq, gamma, beta, ker);
    hipLaunchKernelGGL(k_inv,    dim3(1024),      dim3(256), 0, stream, x, ker, out);
}